// Round 13
// baseline (828.934 us; speedup 1.0000x reference)
//
#include <hip/hip_runtime.h>
#include <hip/hip_bf16.h>
#include <stdint.h>

#define D_MODEL 1024
#define D_FF    4096
#define N_EXP   8
#define TOPK    2
#define NTOK    8192
#define NASSIGN (NTOK*TOPK)

#define BM 128
#define BN 128
#define BN1 256        // gemm1 N-tile (r13): +33% arithmetic intensity
#define BK 64
#define THREADS 256

typedef __bf16 bf16_t;
typedef __attribute__((ext_vector_type(8))) bf16_t bf16x8;
typedef __attribute__((ext_vector_type(4))) float f32x4;

__device__ __forceinline__ unsigned short f2bf(float f) {
    bf16_t b = (bf16_t)f;
    return __builtin_bit_cast(unsigned short, b);
}

__device__ __forceinline__ void gload_lds16(const void* g, void* l) {
    __builtin_amdgcn_global_load_lds(
        (const __attribute__((address_space(1))) void*)g,
        (__attribute__((address_space(3))) void*)l, 16, 0, 0);
}

// ---------------- fp32 -> bf16 convert: W1 and W2, 8 floats/thread/iter ----------------
__global__ void cvt_both_kernel(const float* __restrict__ W1, unsigned short* __restrict__ o1, long n1,
                                const float* __restrict__ W2, unsigned short* __restrict__ o2, long n2) {
    long stride = (long)gridDim.x * blockDim.x;
    long q1 = n1 / 8, q2 = n2 / 8;
    for (long i = (long)blockIdx.x * blockDim.x + threadIdx.x; i < q1 + q2; i += stride) {
        const float4* src; ushort4* dst; long k;
        if (i < q1) { src = (const float4*)W1; dst = (ushort4*)o1; k = i; }
        else        { src = (const float4*)W2; dst = (ushort4*)o2; k = i - q1; }
        float4 v0 = src[2 * k];
        float4 v1 = src[2 * k + 1];
        ushort4 a, b;
        a.x = f2bf(v0.x); a.y = f2bf(v0.y); a.z = f2bf(v0.z); a.w = f2bf(v0.w);
        b.x = f2bf(v1.x); b.y = f2bf(v1.y); b.z = f2bf(v1.z); b.w = f2bf(v1.w);
        dst[2 * k] = a;
        dst[2 * k + 1] = b;
    }
}

// ---------------- router (fused: also emits x in bf16) ----------------
__global__ __launch_bounds__(64) void router_kernel(
        const float* __restrict__ x, const float* __restrict__ gw,
        int* __restrict__ counts, int* __restrict__ ltok, float* __restrict__ lw,
        unsigned short* __restrict__ xb) {
    int n = blockIdx.x;
    int lane = threadIdx.x;
    const float* xr = x + (size_t)n * D_MODEL;
    unsigned short* xbr = xb + (size_t)n * D_MODEL;
    float acc[N_EXP];
    #pragma unroll
    for (int e = 0; e < N_EXP; e++) acc[e] = 0.f;
    #pragma unroll
    for (int i = 0; i < 4; i++) {
        int j = lane + i * 64;                  // float4 index
        float4 v = ((const float4*)xr)[j];
        ushort4 o;
        o.x = f2bf(v.x); o.y = f2bf(v.y); o.z = f2bf(v.z); o.w = f2bf(v.w);
        ((ushort4*)xbr)[j] = o;
        int d = j * 4;
        #pragma unroll
        for (int e = 0; e < N_EXP; e++) {
            const float* g = gw + e * D_MODEL + d;
            acc[e] += v.x * g[0] + v.y * g[1] + v.z * g[2] + v.w * g[3];
        }
    }
    #pragma unroll
    for (int e = 0; e < N_EXP; e++) {
        #pragma unroll
        for (int off = 32; off > 0; off >>= 1)
            acc[e] += __shfl_down(acc[e], off);
    }
    if (lane == 0) {
        float mx = acc[0];
        #pragma unroll
        for (int e = 1; e < N_EXP; e++) mx = fmaxf(mx, acc[e]);
        float p[N_EXP];
        float s = 0.f;
        #pragma unroll
        for (int e = 0; e < N_EXP; e++) { p[e] = expf(acc[e] - mx); s += p[e]; }
        float inv = 1.f / s;
        #pragma unroll
        for (int e = 0; e < N_EXP; e++) p[e] *= inv;
        int i0 = 0;
        #pragma unroll
        for (int e = 1; e < N_EXP; e++) if (p[e] > p[i0]) i0 = e;
        int i1 = (i0 == 0) ? 1 : 0;
        #pragma unroll
        for (int e = 0; e < N_EXP; e++) if (e != i0 && p[e] > p[i1]) i1 = e;
        float s2 = p[i0] + p[i1] + 1e-9f;
        float w0 = p[i0] / s2, w1 = p[i1] / s2;
        int pos0 = atomicAdd(&counts[i0], 1);
        ltok[i0 * NTOK + pos0] = n; lw[i0 * NTOK + pos0] = w0;
        int pos1 = atomicAdd(&counts[i1], 1);
        ltok[i1 * NTOK + pos1] = n; lw[i1 * NTOK + pos1] = w1;
    }
}

// ---------------- exclusive scan over 8 expert counts ----------------
__global__ void scan_kernel(const int* __restrict__ counts, int* __restrict__ offs) {
    if (threadIdx.x == 0 && blockIdx.x == 0) {
        int s = 0;
        for (int e = 0; e < N_EXP; e++) { offs[e] = s; s += counts[e]; }
    }
}

// =====================================================================
// r13: gemm2 FROZEN at r12 config (222us measured, FETCH~ideal).
// gemm1: 128x256 tile (48KB LDS, still 3 blocks/CU; +33% FLOP/staged-byte;
// grid stays 8/CU deep). cvt: 8 floats/thread/iter, grid 2048.
// =====================================================================

// GEMM1: h = relu(X_gathered @ W1[e]^T + b1[e]),  128x256 tile
__global__ __launch_bounds__(THREADS, 3) void gemm1_kernel(
        const unsigned short* __restrict__ xb, const unsigned short* __restrict__ w1b,
        const float* __restrict__ b1,
        const int* __restrict__ counts, const int* __restrict__ offs,
        const int* __restrict__ ltok,
        unsigned short* __restrict__ hb) {
    const int NTM = NTOK / BM;   // 64 (worst case)
    int b = blockIdx.x;
    int e = b & 7;               // expert -> XCD
    int idx = b >> 3;
    int nt = idx / NTM;          // W-panel major
    int mt = idx % NTM;
    int cnt = counts[e];
    if (mt * BM >= cnt) return;

    __shared__ __align__(16) unsigned short As[BM * BK];    // 16 KB
    __shared__ __align__(16) unsigned short Bs[BN1 * BK];   // 32 KB

    int t = threadIdx.x;
    int lane = t & 63, w = t >> 6;     // 4 waves
    int wr = w >> 1, wc = w & 1;       // 2 x 2 (wave tile 64 x 128)

    int srow = t >> 3;                       // 0..31
    int schunk = (t & 7) ^ (srow & 7);
    const unsigned short* aptr[4];
    const unsigned short* bptr[8];
    #pragma unroll
    for (int j = 0; j < 4; j++) {
        int rr = srow + j * 32;
        int slot = mt * BM + rr;
        int cs = slot < cnt ? slot : (cnt - 1);
        int tok = ltok[e * NTOK + cs];
        aptr[j] = xb + (size_t)tok * D_MODEL + schunk * 8;
    }
    #pragma unroll
    for (int j = 0; j < 8; j++) {
        int rr = srow + j * 32;
        bptr[j] = w1b + ((size_t)e * D_FF + nt * BN1 + rr) * D_MODEL + schunk * 8;
    }
    char* As_b = (char*)As;
    char* Bs_b = (char*)Bs;

    int arow_base = wr * 64 + (lane & 15);
    int brow_base = wc * 128 + (lane & 15);
    int ch[2];
    #pragma unroll
    for (int ks = 0; ks < 2; ks++)
        ch[ks] = ((ks * 4 + (lane >> 4)) ^ (lane & 7)) << 4;

    f32x4 acc[4][8];
    #pragma unroll
    for (int m = 0; m < 4; m++)
        #pragma unroll
        for (int n = 0; n < 8; n++)
            acc[m][n] = (f32x4){0.f, 0.f, 0.f, 0.f};

    for (int k0 = 0; k0 < D_MODEL; k0 += BK) {
        #pragma unroll
        for (int j = 0; j < 4; j++)
            gload_lds16(aptr[j] + k0, As_b + j * 4096 + t * 16);
        #pragma unroll
        for (int j = 0; j < 8; j++)
            gload_lds16(bptr[j] + k0, Bs_b + j * 4096 + t * 16);
        __syncthreads();
        #pragma unroll
        for (int ks = 0; ks < 2; ks++) {
            bf16x8 af[4], bf[8];
            #pragma unroll
            for (int m = 0; m < 4; m++)
                af[m] = *(const bf16x8*)(As_b + (size_t)(arow_base + m * 16) * 128 + ch[ks]);
            #pragma unroll
            for (int n = 0; n < 8; n++)
                bf[n] = *(const bf16x8*)(Bs_b + (size_t)(brow_base + n * 16) * 128 + ch[ks]);
            #pragma unroll
            for (int m = 0; m < 4; m++)
                #pragma unroll
                for (int n = 0; n < 8; n++)
                    acc[m][n] = __builtin_amdgcn_mfma_f32_16x16x32_bf16(af[m], bf[n], acc[m][n], 0, 0, 0);
        }
        __syncthreads();
    }

    int hbase = offs[e];
    float biasv[8];
    #pragma unroll
    for (int n = 0; n < 8; ++n)
        biasv[n] = b1[e * D_FF + nt * BN1 + wc * 128 + n * 16 + (lane & 15)];
    #pragma unroll
    for (int m = 0; m < 4; ++m) {
        int s0 = mt * BM + wr * 64 + m * 16 + (lane >> 4) * 4;
        #pragma unroll
        for (int rq = 0; rq < 4; ++rq) {
            int s = s0 + rq;
            if (s < cnt) {
                size_t rowoff = (size_t)(hbase + s) * D_FF + nt * BN1 + wc * 128 + (lane & 15);
                #pragma unroll
                for (int n = 0; n < 8; ++n) {
                    float v = fmaxf(acc[m][n][rq] + biasv[n], 0.f);
                    hb[rowoff + n * 16] = f2bf(v);
                }
            }
        }
    }
}

// GEMM2: y = h @ W2[e]^T + b2[e]; weighted atomic scatter to out  (r12 frozen)
__global__ __launch_bounds__(THREADS, 3) void gemm2_kernel(
        const unsigned short* __restrict__ hb, const unsigned short* __restrict__ w2b,
        const float* __restrict__ b2,
        const int* __restrict__ counts, const int* __restrict__ offs,
        const int* __restrict__ ltok, const float* __restrict__ lw,
        float* __restrict__ out) {
    const int NTM = NTOK / BM;     // 64
    int b = blockIdx.x;
    int e = b & 7;
    int idx = b >> 3;
    int nt = idx / NTM;
    int mt = idx % NTM;
    int cnt = counts[e];
    if (mt * BM >= cnt) return;
    int hbase = offs[e];

    __shared__ __align__(16) unsigned short As[BM * BK];
    __shared__ __align__(16) unsigned short Bs[BN * BK];

    int t = threadIdx.x;
    int lane = t & 63, w = t >> 6;
    int wr = w >> 1, wc = w & 1;

    int srow = t >> 3;
    int schunk = (t & 7) ^ (srow & 7);
    const unsigned short* aptr[4];
    const unsigned short* bptr[4];
    #pragma unroll
    for (int j = 0; j < 4; j++) {
        int rr = srow + j * 32;
        int slot = mt * BM + rr;
        int cs = slot < cnt ? slot : (cnt - 1);
        aptr[j] = hb + (size_t)(hbase + cs) * D_FF + schunk * 8;
        bptr[j] = w2b + ((size_t)e * D_MODEL + nt * BN + rr) * D_FF + schunk * 8;
    }
    char* As_b = (char*)As;
    char* Bs_b = (char*)Bs;

    int arow_base = wr * 64 + (lane & 15);
    int brow_base = wc * 64 + (lane & 15);
    int ch[2];
    #pragma unroll
    for (int ks = 0; ks < 2; ks++)
        ch[ks] = ((ks * 4 + (lane >> 4)) ^ (lane & 7)) << 4;

    f32x4 acc[4][4];
    #pragma unroll
    for (int m = 0; m < 4; m++)
        #pragma unroll
        for (int n = 0; n < 4; n++)
            acc[m][n] = (f32x4){0.f, 0.f, 0.f, 0.f};

    for (int k0 = 0; k0 < D_FF; k0 += BK) {
        #pragma unroll
        for (int j = 0; j < 4; j++) {
            gload_lds16(aptr[j] + k0, As_b + j * 4096 + t * 16);
            gload_lds16(bptr[j] + k0, Bs_b + j * 4096 + t * 16);
        }
        __syncthreads();
        bf16x8 af[2][4], bf[2][4];
        #pragma unroll
        for (int ks = 0; ks < 2; ks++) {
            #pragma unroll
            for (int m = 0; m < 4; m++)
                af[ks][m] = *(const bf16x8*)(As_b + (size_t)(arow_base + m * 16) * 128 + ch[ks]);
            #pragma unroll
            for (int n = 0; n < 4; n++)
                bf[ks][n] = *(const bf16x8*)(Bs_b + (size_t)(brow_base + n * 16) * 128 + ch[ks]);
        }
        #pragma unroll
        for (int ks = 0; ks < 2; ks++)
            #pragma unroll
            for (int m = 0; m < 4; m++)
                #pragma unroll
                for (int n = 0; n < 4; n++)
                    acc[m][n] = __builtin_amdgcn_mfma_f32_16x16x32_bf16(af[ks][m], bf[ks][n], acc[m][n], 0, 0, 0);
        __syncthreads();
    }

    int lbase = e * NTOK;
    float biasv[4];
    #pragma unroll
    for (int n = 0; n < 4; ++n)
        biasv[n] = b2[e * D_MODEL + nt * BN + wc * 64 + n * 16 + (lane & 15)];
    #pragma unroll
    for (int m = 0; m < 4; ++m) {
        int s0 = mt * BM + wr * 64 + m * 16 + (lane >> 4) * 4;
        #pragma unroll
        for (int rq = 0; rq < 4; ++rq) {
            int s = s0 + rq;
            if (s >= cnt) continue;
            int tok = ltok[lbase + s];
            float wgt = lw[lbase + s];
            float* orow = out + (size_t)tok * D_MODEL + nt * BN + wc * 64 + (lane & 15);
            #pragma unroll
            for (int n = 0; n < 4; ++n)
                atomicAdd(orow + n * 16, wgt * (acc[m][n][rq] + biasv[n]));
        }
    }
}

extern "C" void kernel_launch(void* const* d_in, const int* in_sizes, int n_in,
                              void* d_out, int out_size, void* d_ws, size_t ws_size,
                              hipStream_t stream) {
    const float* x  = (const float*)d_in[0];
    const float* gw = (const float*)d_in[1];
    const float* W1 = (const float*)d_in[2];
    const float* b1 = (const float*)d_in[3];
    const float* W2 = (const float*)d_in[4];
    const float* b2 = (const float*)d_in[5];
    float* out = (float*)d_out;

    char* ws = (char*)d_ws;
    size_t off = 0;
    auto alloc = [&](size_t bytes) -> char* {
        char* p = ws + off;
        off += (bytes + 255) & ~(size_t)255;
        return p;
    };
    unsigned short* xb  = (unsigned short*)alloc((size_t)NTOK * D_MODEL * 2);
    unsigned short* w1b = (unsigned short*)alloc((size_t)N_EXP * D_FF * D_MODEL * 2);
    unsigned short* w2b = (unsigned short*)alloc((size_t)N_EXP * D_MODEL * D_FF * 2);
    unsigned short* hb  = (unsigned short*)alloc((size_t)NASSIGN * D_FF * 2);
    int*   counts = (int*)alloc(256);
    int*   offs   = (int*)alloc(256);
    int*   ltok   = (int*)alloc((size_t)N_EXP * NTOK * 4);
    float* lw     = (float*)alloc((size_t)N_EXP * NTOK * 4);

    hipMemsetAsync(out, 0, (size_t)out_size * 4, stream);
    hipMemsetAsync(counts, 0, 256, stream);
    cvt_both_kernel<<<2048, 256, 0, stream>>>(
        W1, w1b, (long)N_EXP * D_FF * D_MODEL, W2, w2b, (long)N_EXP * D_MODEL * D_FF);
    router_kernel<<<NTOK, 64, 0, stream>>>(x, gw, counts, ltok, lw, xb);
    scan_kernel<<<1, 64, 0, stream>>>(counts, offs);
    gemm1_kernel<<<N_EXP * (NTOK / BM) * (D_FF / BN1), THREADS, 0, stream>>>(
        xb, w1b, b1, counts, offs, ltok, hb);
    gemm2_kernel<<<N_EXP * (NTOK / BM) * (D_MODEL / BN), THREADS, 0, stream>>>(
        hb, w2b, b2, counts, offs, ltok, lw, out);
}

// Round 14
// 674.039 us; speedup vs baseline: 1.2298x; 1.2298x over previous
//
#include <hip/hip_runtime.h>
#include <hip/hip_bf16.h>
#include <stdint.h>

#define D_MODEL 1024
#define D_FF    4096
#define N_EXP   8
#define TOPK    2
#define NTOK    8192
#define NASSIGN (NTOK*TOPK)

#define BM 128
#define BN 128
#define BK 64
#define THREADS 256

typedef __bf16 bf16_t;
typedef __attribute__((ext_vector_type(8))) bf16_t bf16x8;
typedef __attribute__((ext_vector_type(4))) float f32x4;
typedef __attribute__((ext_vector_type(8))) unsigned short u16x8;

__device__ __forceinline__ unsigned short f2bf(float f) {
    bf16_t b = (bf16_t)f;
    return __builtin_bit_cast(unsigned short, b);
}

__device__ __forceinline__ void gload_lds16(const void* g, void* l) {
    __builtin_amdgcn_global_load_lds(
        (const __attribute__((address_space(1))) void*)g,
        (__attribute__((address_space(3))) void*)l, 16, 0, 0);
}

// ---------------- fp32 -> bf16 convert: W1 and W2, 8 floats/thread/iter ----------------
__global__ void cvt_both_kernel(const float* __restrict__ W1, unsigned short* __restrict__ o1, long n1,
                                const float* __restrict__ W2, unsigned short* __restrict__ o2, long n2) {
    long stride = (long)gridDim.x * blockDim.x;
    long q1 = n1 / 8, q2 = n2 / 8;
    for (long i = (long)blockIdx.x * blockDim.x + threadIdx.x; i < q1 + q2; i += stride) {
        const float4* src; ushort4* dst; long k;
        if (i < q1) { src = (const float4*)W1; dst = (ushort4*)o1; k = i; }
        else        { src = (const float4*)W2; dst = (ushort4*)o2; k = i - q1; }
        float4 v0 = src[2 * k];
        float4 v1 = src[2 * k + 1];
        ushort4 a, b;
        a.x = f2bf(v0.x); a.y = f2bf(v0.y); a.z = f2bf(v0.z); a.w = f2bf(v0.w);
        b.x = f2bf(v1.x); b.y = f2bf(v1.y); b.z = f2bf(v1.z); b.w = f2bf(v1.w);
        dst[2 * k] = a;
        dst[2 * k + 1] = b;
    }
}

// ---------------- router (fused: also emits x in bf16) ----------------
__global__ __launch_bounds__(64) void router_kernel(
        const float* __restrict__ x, const float* __restrict__ gw,
        int* __restrict__ counts, int* __restrict__ ltok, float* __restrict__ lw,
        unsigned short* __restrict__ xb) {
    int n = blockIdx.x;
    int lane = threadIdx.x;
    const float* xr = x + (size_t)n * D_MODEL;
    unsigned short* xbr = xb + (size_t)n * D_MODEL;
    float acc[N_EXP];
    #pragma unroll
    for (int e = 0; e < N_EXP; e++) acc[e] = 0.f;
    #pragma unroll
    for (int i = 0; i < 4; i++) {
        int j = lane + i * 64;                  // float4 index
        float4 v = ((const float4*)xr)[j];
        ushort4 o;
        o.x = f2bf(v.x); o.y = f2bf(v.y); o.z = f2bf(v.z); o.w = f2bf(v.w);
        ((ushort4*)xbr)[j] = o;
        int d = j * 4;
        #pragma unroll
        for (int e = 0; e < N_EXP; e++) {
            const float* g = gw + e * D_MODEL + d;
            acc[e] += v.x * g[0] + v.y * g[1] + v.z * g[2] + v.w * g[3];
        }
    }
    #pragma unroll
    for (int e = 0; e < N_EXP; e++) {
        #pragma unroll
        for (int off = 32; off > 0; off >>= 1)
            acc[e] += __shfl_down(acc[e], off);
    }
    if (lane == 0) {
        float mx = acc[0];
        #pragma unroll
        for (int e = 1; e < N_EXP; e++) mx = fmaxf(mx, acc[e]);
        float p[N_EXP];
        float s = 0.f;
        #pragma unroll
        for (int e = 0; e < N_EXP; e++) { p[e] = expf(acc[e] - mx); s += p[e]; }
        float inv = 1.f / s;
        #pragma unroll
        for (int e = 0; e < N_EXP; e++) p[e] *= inv;
        int i0 = 0;
        #pragma unroll
        for (int e = 1; e < N_EXP; e++) if (p[e] > p[i0]) i0 = e;
        int i1 = (i0 == 0) ? 1 : 0;
        #pragma unroll
        for (int e = 0; e < N_EXP; e++) if (e != i0 && p[e] > p[i1]) i1 = e;
        float s2 = p[i0] + p[i1] + 1e-9f;
        float w0 = p[i0] / s2, w1 = p[i1] / s2;
        int pos0 = atomicAdd(&counts[i0], 1);
        ltok[i0 * NTOK + pos0] = n; lw[i0 * NTOK + pos0] = w0;
        int pos1 = atomicAdd(&counts[i1], 1);
        ltok[i1 * NTOK + pos1] = n; lw[i1 * NTOK + pos1] = w1;
    }
}

// ---------------- exclusive scan over 8 expert counts ----------------
__global__ void scan_kernel(const int* __restrict__ counts, int* __restrict__ offs) {
    if (threadIdx.x == 0 && blockIdx.x == 0) {
        int s = 0;
        for (int e = 0; e < N_EXP; e++) { offs[e] = s; s += counts[e]; }
    }
}

// =====================================================================
// r14 = r12 (best measured: 681us; gemm2 222us FETCH~ideal) with ONE fix:
// gemm1's hb store was 2-B scattered shorts -> partial-line write
// amplification (r13 @BN=256 exposed WRITE=675MB for 134MB of payload).
// New epilogue: per-wave LDS repack ([16][72] bf16, stride 144B = ~2-way
// banks, reusing As after K-loop) then ushort8 full-line coalesced
// stores (8 lanes = one 128B line per row). BN1=256 reverted (falsified:
// traffic-bound, MfmaUtil 16%).
// =====================================================================

// GEMM1: h = relu(X_gathered @ W1[e]^T + b1[e])
__global__ __launch_bounds__(THREADS, 3) void gemm1_kernel(
        const unsigned short* __restrict__ xb, const unsigned short* __restrict__ w1b,
        const float* __restrict__ b1,
        const int* __restrict__ counts, const int* __restrict__ offs,
        const int* __restrict__ ltok,
        unsigned short* __restrict__ hb) {
    const int NTM = NTOK / BM;   // 64 (worst case)
    int b = blockIdx.x;
    int e = b & 7;               // expert -> XCD
    int idx = b >> 3;
    int nt = idx / NTM;          // W-panel major: co-resident blocks share nt
    int mt = idx % NTM;
    int cnt = counts[e];
    if (mt * BM >= cnt) return;

    __shared__ __align__(16) unsigned short As[BM * BK];   // 16 KB
    __shared__ __align__(16) unsigned short Bs[BN * BK];   // 16 KB

    int t = threadIdx.x;
    int lane = t & 63, w = t >> 6;     // 4 waves
    int wr = w >> 1, wc = w & 1;       // 2 x 2

    int srow = t >> 3;                       // 0..31
    int schunk = (t & 7) ^ (srow & 7);
    const unsigned short* aptr[4];
    const unsigned short* bptr[4];
    #pragma unroll
    for (int j = 0; j < 4; j++) {
        int rr = srow + j * 32;
        int slot = mt * BM + rr;
        int cs = slot < cnt ? slot : (cnt - 1);
        int tok = ltok[e * NTOK + cs];
        aptr[j] = xb + (size_t)tok * D_MODEL + schunk * 8;
        bptr[j] = w1b + ((size_t)e * D_FF + nt * BN + rr) * D_MODEL + schunk * 8;
    }
    char* As_b = (char*)As;
    char* Bs_b = (char*)Bs;

    int arow_base = wr * 64 + (lane & 15);
    int brow_base = wc * 64 + (lane & 15);
    int ch[2];
    #pragma unroll
    for (int ks = 0; ks < 2; ks++)
        ch[ks] = ((ks * 4 + (lane >> 4)) ^ (lane & 7)) << 4;

    f32x4 acc[4][4];
    #pragma unroll
    for (int m = 0; m < 4; m++)
        #pragma unroll
        for (int n = 0; n < 4; n++)
            acc[m][n] = (f32x4){0.f, 0.f, 0.f, 0.f};

    for (int k0 = 0; k0 < D_MODEL; k0 += BK) {
        #pragma unroll
        for (int j = 0; j < 4; j++) {
            gload_lds16(aptr[j] + k0, As_b + j * 4096 + t * 16);
            gload_lds16(bptr[j] + k0, Bs_b + j * 4096 + t * 16);
        }
        __syncthreads();
        bf16x8 af[2][4], bf[2][4];
        #pragma unroll
        for (int ks = 0; ks < 2; ks++) {
            #pragma unroll
            for (int m = 0; m < 4; m++)
                af[ks][m] = *(const bf16x8*)(As_b + (size_t)(arow_base + m * 16) * 128 + ch[ks]);
            #pragma unroll
            for (int n = 0; n < 4; n++)
                bf[ks][n] = *(const bf16x8*)(Bs_b + (size_t)(brow_base + n * 16) * 128 + ch[ks]);
        }
        #pragma unroll
        for (int ks = 0; ks < 2; ks++)
            #pragma unroll
            for (int m = 0; m < 4; m++)
                #pragma unroll
                for (int n = 0; n < 4; n++)
                    acc[m][n] = __builtin_amdgcn_mfma_f32_16x16x32_bf16(af[ks][m], bf[ks][n], acc[m][n], 0, 0, 0);
        __syncthreads();
    }

    // ---- epilogue: relu+bias, per-wave LDS repack, coalesced ushort8 stores
    int hbase = offs[e];
    float biasv[4];
    #pragma unroll
    for (int n = 0; n < 4; ++n)
        biasv[n] = b1[e * D_FF + nt * BN + wc * 64 + n * 16 + (lane & 15)];
    // wave-private chunk [16][72] bf16 = 2304 B, 16B-aligned stride per wave
    unsigned short* Hs = (unsigned short*)(As_b) + w * 1216;   // 1216 us = 2432 B
    #pragma unroll
    for (int m = 0; m < 4; ++m) {
        #pragma unroll
        for (int n = 0; n < 4; ++n) {
            #pragma unroll
            for (int rq = 0; rq < 4; ++rq) {
                int lr = (lane >> 4) * 4 + rq;      // 0..15
                int lc = n * 16 + (lane & 15);      // 0..63
                float v = fmaxf(acc[m][n][rq] + biasv[n], 0.f);
                Hs[lr * 72 + lc] = f2bf(v);
            }
        }
        // read back coalesced: 8 lanes cover one 128B row-line
        #pragma unroll
        for (int half = 0; half < 2; ++half) {
            int lr = half * 8 + (lane >> 3);        // 0..15
            u16x8 vv = *(const u16x8*)(Hs + lr * 72 + (lane & 7) * 8);
            int s = mt * BM + wr * 64 + m * 16 + lr;
            if (s < cnt) {
                *(u16x8*)(hb + (size_t)(hbase + s) * D_FF + nt * BN + wc * 64 + (lane & 7) * 8) = vv;
            }
        }
    }
}

// GEMM2: y = h @ W2[e]^T + b2[e]; weighted atomic scatter to out  (r12 frozen)
__global__ __launch_bounds__(THREADS, 3) void gemm2_kernel(
        const unsigned short* __restrict__ hb, const unsigned short* __restrict__ w2b,
        const float* __restrict__ b2,
        const int* __restrict__ counts, const int* __restrict__ offs,
        const int* __restrict__ ltok, const float* __restrict__ lw,
        float* __restrict__ out) {
    const int NTM = NTOK / BM;     // 64
    int b = blockIdx.x;
    int e = b & 7;
    int idx = b >> 3;
    int nt = idx / NTM;
    int mt = idx % NTM;
    int cnt = counts[e];
    if (mt * BM >= cnt) return;
    int hbase = offs[e];

    __shared__ __align__(16) unsigned short As[BM * BK];
    __shared__ __align__(16) unsigned short Bs[BN * BK];

    int t = threadIdx.x;
    int lane = t & 63, w = t >> 6;
    int wr = w >> 1, wc = w & 1;

    int srow = t >> 3;
    int schunk = (t & 7) ^ (srow & 7);
    const unsigned short* aptr[4];
    const unsigned short* bptr[4];
    #pragma unroll
    for (int j = 0; j < 4; j++) {
        int rr = srow + j * 32;
        int slot = mt * BM + rr;
        int cs = slot < cnt ? slot : (cnt - 1);
        aptr[j] = hb + (size_t)(hbase + cs) * D_FF + schunk * 8;
        bptr[j] = w2b + ((size_t)e * D_MODEL + nt * BN + rr) * D_FF + schunk * 8;
    }
    char* As_b = (char*)As;
    char* Bs_b = (char*)Bs;

    int arow_base = wr * 64 + (lane & 15);
    int brow_base = wc * 64 + (lane & 15);
    int ch[2];
    #pragma unroll
    for (int ks = 0; ks < 2; ks++)
        ch[ks] = ((ks * 4 + (lane >> 4)) ^ (lane & 7)) << 4;

    f32x4 acc[4][4];
    #pragma unroll
    for (int m = 0; m < 4; m++)
        #pragma unroll
        for (int n = 0; n < 4; n++)
            acc[m][n] = (f32x4){0.f, 0.f, 0.f, 0.f};

    for (int k0 = 0; k0 < D_FF; k0 += BK) {
        #pragma unroll
        for (int j = 0; j < 4; j++) {
            gload_lds16(aptr[j] + k0, As_b + j * 4096 + t * 16);
            gload_lds16(bptr[j] + k0, Bs_b + j * 4096 + t * 16);
        }
        __syncthreads();
        bf16x8 af[2][4], bf[2][4];
        #pragma unroll
        for (int ks = 0; ks < 2; ks++) {
            #pragma unroll
            for (int m = 0; m < 4; m++)
                af[ks][m] = *(const bf16x8*)(As_b + (size_t)(arow_base + m * 16) * 128 + ch[ks]);
            #pragma unroll
            for (int n = 0; n < 4; n++)
                bf[ks][n] = *(const bf16x8*)(Bs_b + (size_t)(brow_base + n * 16) * 128 + ch[ks]);
        }
        #pragma unroll
        for (int ks = 0; ks < 2; ks++)
            #pragma unroll
            for (int m = 0; m < 4; m++)
                #pragma unroll
                for (int n = 0; n < 4; n++)
                    acc[m][n] = __builtin_amdgcn_mfma_f32_16x16x32_bf16(af[ks][m], bf[ks][n], acc[m][n], 0, 0, 0);
        __syncthreads();
    }

    int lbase = e * NTOK;
    float biasv[4];
    #pragma unroll
    for (int n = 0; n < 4; ++n)
        biasv[n] = b2[e * D_MODEL + nt * BN + wc * 64 + n * 16 + (lane & 15)];
    #pragma unroll
    for (int m = 0; m < 4; ++m) {
        int s0 = mt * BM + wr * 64 + m * 16 + (lane >> 4) * 4;
        #pragma unroll
        for (int rq = 0; rq < 4; ++rq) {
            int s = s0 + rq;
            if (s >= cnt) continue;
            int tok = ltok[lbase + s];
            float wgt = lw[lbase + s];
            float* orow = out + (size_t)tok * D_MODEL + nt * BN + wc * 64 + (lane & 15);
            #pragma unroll
            for (int n = 0; n < 4; ++n)
                atomicAdd(orow + n * 16, wgt * (acc[m][n][rq] + biasv[n]));
        }
    }
}

extern "C" void kernel_launch(void* const* d_in, const int* in_sizes, int n_in,
                              void* d_out, int out_size, void* d_ws, size_t ws_size,
                              hipStream_t stream) {
    const float* x  = (const float*)d_in[0];
    const float* gw = (const float*)d_in[1];
    const float* W1 = (const float*)d_in[2];
    const float* b1 = (const float*)d_in[3];
    const float* W2 = (const float*)d_in[4];
    const float* b2 = (const float*)d_in[5];
    float* out = (float*)d_out;

    char* ws = (char*)d_ws;
    size_t off = 0;
    auto alloc = [&](size_t bytes) -> char* {
        char* p = ws + off;
        off += (bytes + 255) & ~(size_t)255;
        return p;
    };
    unsigned short* xb  = (unsigned short*)alloc((size_t)NTOK * D_MODEL * 2);
    unsigned short* w1b = (unsigned short*)alloc((size_t)N_EXP * D_FF * D_MODEL * 2);
    unsigned short* w2b = (unsigned short*)alloc((size_t)N_EXP * D_MODEL * D_FF * 2);
    unsigned short* hb  = (unsigned short*)alloc((size_t)NASSIGN * D_FF * 2);
    int*   counts = (int*)alloc(256);
    int*   offs   = (int*)alloc(256);
    int*   ltok   = (int*)alloc((size_t)N_EXP * NTOK * 4);
    float* lw     = (float*)alloc((size_t)N_EXP * NTOK * 4);

    hipMemsetAsync(out, 0, (size_t)out_size * 4, stream);
    hipMemsetAsync(counts, 0, 256, stream);
    cvt_both_kernel<<<2048, 256, 0, stream>>>(
        W1, w1b, (long)N_EXP * D_FF * D_MODEL, W2, w2b, (long)N_EXP * D_MODEL * D_FF);
    router_kernel<<<NTOK, 64, 0, stream>>>(x, gw, counts, ltok, lw, xb);
    scan_kernel<<<1, 64, 0, stream>>>(counts, offs);
    gemm1_kernel<<<N_EXP * (NTOK / BM) * (D_FF / BN), THREADS, 0, stream>>>(
        xb, w1b, b1, counts, offs, ltok, hb);
    gemm2_kernel<<<N_EXP * (NTOK / BM) * (D_MODEL / BN), THREADS, 0, stream>>>(
        hb, w2b, b2, counts, offs, ltok, lw, out);
}